// Round 2
// baseline (213.700 us; speedup 1.0000x reference)
//
#include <hip/hip_runtime.h>

#define NB 256
#define NO 10
#define NI 1152
#define NK 8
#define ND 16
#define IC 4

__device__ __forceinline__ float dot8(const float* __restrict__ w, const float* x){
  float a = 0.f;
  #pragma unroll
  for (int k = 0; k < NK; ++k) a = fmaf(w[k], x[k], a);
  return a;
}

// xT[(i*NK+k)*NB + b] = x[(b*NI+i)*NK + k]
__global__ __launch_bounds__(256) void k_transpose(const float* __restrict__ x,
                                                   float* __restrict__ xT){
  __shared__ float tile[32][33];
  int m0 = blockIdx.x * 32;   // ik index
  int b0 = blockIdx.y * 32;   // b index
  int tx = threadIdx.x, ty = threadIdx.y;
  #pragma unroll
  for (int r = 0; r < 32; r += 8)
    tile[ty + r][tx] = x[(size_t)(b0 + ty + r) * (NI * NK) + (m0 + tx)];
  __syncthreads();
  #pragma unroll
  for (int r = 0; r < 32; r += 8)
    xT[(size_t)(m0 + ty + r) * NB + (b0 + tx)] = tile[tx][ty + r];
}

// Pass 0: S0[o,d,b] = 0.1 * sum_i u[o,i,b,d];  usq[o,i,b] = |u|^2
__global__ __launch_bounds__(256) void k_pass0(const float* __restrict__ xT,
                                               const float* __restrict__ W,
                                               float* __restrict__ usq,
                                               float* __restrict__ S0){
  int o = blockIdx.y, i0 = blockIdx.x * IC, b = threadIdx.x;
  float acc[ND];
  #pragma unroll
  for (int d = 0; d < ND; ++d) acc[d] = 0.f;
  for (int ii = 0; ii < IC; ++ii){
    int i = i0 + ii;
    const float* Wp = W + ((size_t)o * NI + i) * (ND * NK);  // wave-uniform -> s_load
    float xr[NK];
    #pragma unroll
    for (int k = 0; k < NK; ++k) xr[k] = xT[((size_t)i * NK + k) * NB + b];
    float us = 0.f;
    #pragma unroll
    for (int d = 0; d < ND; ++d){
      float u = dot8(Wp + d * NK, xr);
      us = fmaf(u, u, us);
      acc[d] += u;
    }
    usq[((size_t)o * NI + i) * NB + b] = us;
  }
  #pragma unroll
  for (int d = 0; d < ND; ++d)
    atomicAdd(&S0[((size_t)o * ND + d) * NB + b], 0.1f * acc[d]);
}

// s2n[o,b] = |S[o,:,b]|^2
__global__ __launch_bounds__(256) void k_s2n(const float* __restrict__ S,
                                             float* __restrict__ s2n){
  int o = blockIdx.x, b = threadIdx.x;
  float s2 = 0.f;
  #pragma unroll
  for (int d = 0; d < ND; ++d){
    float s = S[((size_t)o * ND + d) * NB + b];
    s2 = fmaf(s, s, s2);
  }
  s2n[o * NB + b] = s2;
}

// dot pass: db from (dot, usq, s2), L update, softmax over o -> C
template<bool FIRST, bool WRITEL>
__global__ __launch_bounds__(256) void k_dot(const float* __restrict__ xT,
                                             const float* __restrict__ W,
                                             const float* __restrict__ usq,
                                             const float* __restrict__ S,
                                             const float* __restrict__ s2n,
                                             float* __restrict__ L,
                                             float* __restrict__ C){
  int i = blockIdx.x, b = threadIdx.x;
  float xr[NK];
  #pragma unroll
  for (int k = 0; k < NK; ++k) xr[k] = xT[((size_t)i * NK + k) * NB + b];
  float l[NO];
  for (int o = 0; o < NO; ++o){
    const float* Wp = W + ((size_t)o * NI + i) * (ND * NK);  // wave-uniform
    float dot = 0.f;
    #pragma unroll
    for (int d = 0; d < ND; ++d){
      float u = dot8(Wp + d * NK, xr);
      dot = fmaf(u, S[((size_t)o * ND + d) * NB + b], dot);
    }
    float us = usq[((size_t)o * NI + i) * NB + b];
    float s2 = s2n[o * NB + b];
    float t2 = fmaxf(s2 - 2.f * dot + us, 0.f);
    float ut = dot - us;
    float db = (t2 / (1.f + t2)) * ut / (sqrtf(t2) + 1e-8f);
    float lo = FIRST ? db : (L[((size_t)o * NI + i) * NB + b] + db);
    if (WRITEL) L[((size_t)o * NI + i) * NB + b] = lo;
    l[o] = lo;
  }
  float m = l[0];
  #pragma unroll
  for (int o = 1; o < NO; ++o) m = fmaxf(m, l[o]);
  float den = 0.f;
  #pragma unroll
  for (int o = 0; o < NO; ++o){ l[o] = __expf(l[o] - m); den += l[o]; }
  float inv = 1.f / den;
  #pragma unroll
  for (int o = 0; o < NO; ++o) C[((size_t)o * NI + i) * NB + b] = l[o] * inv;
}

// accumulate pass: S[o,d,b] = sum_i C[o,i,b] * (W[o,i] x[b,i])_d  via W·(c·x)
__global__ __launch_bounds__(256) void k_acc(const float* __restrict__ xT,
                                             const float* __restrict__ W,
                                             const float* __restrict__ C,
                                             float* __restrict__ S){
  int o = blockIdx.y, i0 = blockIdx.x * IC, b = threadIdx.x;
  float acc[ND];
  #pragma unroll
  for (int d = 0; d < ND; ++d) acc[d] = 0.f;
  for (int ii = 0; ii < IC; ++ii){
    int i = i0 + ii;
    const float* Wp = W + ((size_t)o * NI + i) * (ND * NK);  // wave-uniform
    float c = C[((size_t)o * NI + i) * NB + b];
    float xc[NK];
    #pragma unroll
    for (int k = 0; k < NK; ++k) xc[k] = c * xT[((size_t)i * NK + k) * NB + b];
    #pragma unroll
    for (int d = 0; d < ND; ++d) acc[d] += dot8(Wp + d * NK, xc);
  }
  #pragma unroll
  for (int d = 0; d < ND; ++d)
    atomicAdd(&S[((size_t)o * ND + d) * NB + b], acc[d]);
}

// out[b][o][d] = squash(S[o,:,b])
__global__ __launch_bounds__(256) void k_final(const float* __restrict__ S,
                                               float* __restrict__ out){
  int o = blockIdx.x, b = threadIdx.x;
  float s[ND], s2 = 0.f;
  #pragma unroll
  for (int d = 0; d < ND; ++d){
    s[d] = S[((size_t)o * ND + d) * NB + b];
    s2 = fmaf(s[d], s[d], s2);
  }
  float sc = (s2 / (1.f + s2)) / (sqrtf(s2) + 1e-8f);
  #pragma unroll
  for (int d = 0; d < ND; ++d) out[((size_t)b * NO + o) * ND + d] = s[d] * sc;
}

extern "C" void kernel_launch(void* const* d_in, const int* in_sizes, int n_in,
                              void* d_out, int out_size, void* d_ws, size_t ws_size,
                              hipStream_t stream){
  const float* x = (const float*)d_in[0];
  // d_in[1] (y) unused by the reference computation.
  const float* W = (const float*)d_in[2];
  float* out = (float*)d_out;
  char* ws = (char*)d_ws;

  const size_t xT_b  = (size_t)NI * NK * NB * sizeof(float);   // 9.4 MB
  const size_t usq_b = (size_t)NO * NI * NB * sizeof(float);   // 11.8 MB
  const size_t L_b   = usq_b;
  const size_t C_b   = usq_b;
  const size_t s2n_b = (size_t)NO * NB * sizeof(float);        // 10 KB
  const size_t S_b   = (size_t)NO * ND * NB * sizeof(float);   // 160 KB

  size_t off = 0;
  float* xT  = (float*)(ws + off); off += xT_b;
  float* usq = (float*)(ws + off); off += usq_b;
  float* L   = (float*)(ws + off); off += L_b;
  float* C   = (float*)(ws + off); off += C_b;
  float* s2n = (float*)(ws + off); off += s2n_b;
  float* S   = (float*)(ws + off); off += S_b;
  (void)ws_size; (void)in_sizes; (void)n_in; (void)out_size;

  k_transpose<<<dim3((NI * NK) / 32, NB / 32), dim3(32, 8), 0, stream>>>(x, xT);

  // iteration 0: uniform c = 0.1  ->  S0, usq
  hipMemsetAsync(S, 0, S_b, stream);
  k_pass0<<<dim3(NI / IC, NO), 256, 0, stream>>>(xT, W, usq, S);
  k_s2n<<<dim3(NO), 256, 0, stream>>>(S, s2n);
  k_dot<true, true><<<dim3(NI), 256, 0, stream>>>(xT, W, usq, S, s2n, L, C);

  // iteration 1
  hipMemsetAsync(S, 0, S_b, stream);
  k_acc<<<dim3(NI / IC, NO), 256, 0, stream>>>(xT, W, C, S);
  k_s2n<<<dim3(NO), 256, 0, stream>>>(S, s2n);
  k_dot<false, false><<<dim3(NI), 256, 0, stream>>>(xT, W, usq, S, s2n, L, C);

  // iteration 2 (final accumulation) + squash
  hipMemsetAsync(S, 0, S_b, stream);
  k_acc<<<dim3(NI / IC, NO), 256, 0, stream>>>(xT, W, C, S);
  k_final<<<dim3(NO), 256, 0, stream>>>(S, out);
}

// Round 3
// 160.278 us; speedup vs baseline: 1.3333x; 1.3333x over previous
//
#include <hip/hip_runtime.h>

#define NB 256
#define NO 10
#define NI 1152
#define NK 8
#define ND 16
#define NCHUNK 72
#define IC 16   // NI / NCHUNK

__device__ __forceinline__ float dot8(const float* __restrict__ w, const float* x){
  float a = 0.f;
  #pragma unroll
  for (int k = 0; k < NK; ++k) a = fmaf(w[k], x[k], a);
  return a;
}

// xT[(i*NK+k)*NB + b] = x[(b*NI+i)*NK + k]
__global__ __launch_bounds__(256) void k_transpose(const float* __restrict__ x,
                                                   float* __restrict__ xT){
  __shared__ float tile[32][33];
  int m0 = blockIdx.x * 32;   // ik index
  int b0 = blockIdx.y * 32;   // b index
  int tx = threadIdx.x, ty = threadIdx.y;
  #pragma unroll
  for (int r = 0; r < 32; r += 8)
    tile[ty + r][tx] = x[(size_t)(b0 + ty + r) * (NI * NK) + (m0 + tx)];
  __syncthreads();
  #pragma unroll
  for (int r = 0; r < 32; r += 8)
    xT[(size_t)(m0 + ty + r) * NB + (b0 + tx)] = tile[tx][ty + r];
}

// Stage 1, iter 0: P[c,o,d,b] = 0.1 * sum_{i in chunk} u_d ; usq[o,i,b] = |u|^2
__global__ __launch_bounds__(256) void k_pass0(const float* __restrict__ xT,
                                               const float* __restrict__ W,
                                               float* __restrict__ usq,
                                               float* __restrict__ P){
  int o = blockIdx.y, c = blockIdx.x, i0 = c * IC, b = threadIdx.x;
  float acc[ND];
  #pragma unroll
  for (int d = 0; d < ND; ++d) acc[d] = 0.f;
  for (int ii = 0; ii < IC; ++ii){
    int i = i0 + ii;
    const float* Wp = W + ((size_t)o * NI + i) * (ND * NK);  // wave-uniform -> s_load
    float xr[NK];
    #pragma unroll
    for (int k = 0; k < NK; ++k) xr[k] = xT[((size_t)i * NK + k) * NB + b];
    float us = 0.f;
    #pragma unroll
    for (int d = 0; d < ND; ++d){
      float u = dot8(Wp + d * NK, xr);
      us = fmaf(u, u, us);
      acc[d] += u;
    }
    usq[((size_t)o * NI + i) * NB + b] = us;
  }
  #pragma unroll
  for (int d = 0; d < ND; ++d)
    P[(((size_t)c * NO + o) * ND + d) * NB + b] = 0.1f * acc[d];
}

// Stage 1, iters 1/2: P[c,o,d,b] = sum_{i in chunk} C[o,i,b] * u_d   (via W·(c·x))
__global__ __launch_bounds__(256) void k_acc(const float* __restrict__ xT,
                                             const float* __restrict__ W,
                                             const float* __restrict__ C,
                                             float* __restrict__ P){
  int o = blockIdx.y, c = blockIdx.x, i0 = c * IC, b = threadIdx.x;
  float acc[ND];
  #pragma unroll
  for (int d = 0; d < ND; ++d) acc[d] = 0.f;
  for (int ii = 0; ii < IC; ++ii){
    int i = i0 + ii;
    const float* Wp = W + ((size_t)o * NI + i) * (ND * NK);  // wave-uniform
    float cw = C[((size_t)o * NI + i) * NB + b];
    float xc[NK];
    #pragma unroll
    for (int k = 0; k < NK; ++k) xc[k] = cw * xT[((size_t)i * NK + k) * NB + b];
    #pragma unroll
    for (int d = 0; d < ND; ++d) acc[d] += dot8(Wp + d * NK, xc);
  }
  #pragma unroll
  for (int d = 0; d < ND; ++d)
    P[(((size_t)c * NO + o) * ND + d) * NB + b] = acc[d];
}

// Stage 2: S[o,d,b] = sum_c P[c,o,d,b]
__global__ __launch_bounds__(256) void k_red(const float* __restrict__ P,
                                             float* __restrict__ S){
  int d = blockIdx.x, o = blockIdx.y, b = threadIdx.x;
  float a = 0.f;
  for (int c = 0; c < NCHUNK; ++c)
    a += P[(((size_t)c * NO + o) * ND + d) * NB + b];
  S[((size_t)o * ND + d) * NB + b] = a;
}

// dot pass: db from (dot, usq, |S|^2), L update, softmax over o -> C
template<bool FIRST, bool WRITEL>
__global__ __launch_bounds__(256) void k_dot(const float* __restrict__ xT,
                                             const float* __restrict__ W,
                                             const float* __restrict__ usq,
                                             const float* __restrict__ S,
                                             float* __restrict__ L,
                                             float* __restrict__ C){
  int i = blockIdx.x, b = threadIdx.x;
  float xr[NK];
  #pragma unroll
  for (int k = 0; k < NK; ++k) xr[k] = xT[((size_t)i * NK + k) * NB + b];
  float l[NO];
  #pragma unroll
  for (int o = 0; o < NO; ++o){
    const float* Wp = W + ((size_t)o * NI + i) * (ND * NK);  // wave-uniform
    float s[ND], s2 = 0.f;
    #pragma unroll
    for (int d = 0; d < ND; ++d){
      s[d] = S[((size_t)o * ND + d) * NB + b];
      s2 = fmaf(s[d], s[d], s2);
    }
    float dot = 0.f;
    #pragma unroll
    for (int d = 0; d < ND; ++d){
      float u = dot8(Wp + d * NK, xr);
      dot = fmaf(u, s[d], dot);
    }
    float us = usq[((size_t)o * NI + i) * NB + b];
    float t2 = fmaxf(s2 - 2.f * dot + us, 0.f);
    float ut = dot - us;
    float db = (t2 / (1.f + t2)) * ut / (sqrtf(t2) + 1e-8f);
    float lo = FIRST ? db : (L[((size_t)o * NI + i) * NB + b] + db);
    if (WRITEL) L[((size_t)o * NI + i) * NB + b] = lo;
    l[o] = lo;
  }
  float m = l[0];
  #pragma unroll
  for (int o = 1; o < NO; ++o) m = fmaxf(m, l[o]);
  float den = 0.f;
  #pragma unroll
  for (int o = 0; o < NO; ++o){ l[o] = __expf(l[o] - m); den += l[o]; }
  float inv = 1.f / den;
  #pragma unroll
  for (int o = 0; o < NO; ++o) C[((size_t)o * NI + i) * NB + b] = l[o] * inv;
}

// out[b][o][d] = squash(S[o,:,b])
__global__ __launch_bounds__(256) void k_final(const float* __restrict__ S,
                                               float* __restrict__ out){
  int o = blockIdx.x, b = threadIdx.x;
  float s[ND], s2 = 0.f;
  #pragma unroll
  for (int d = 0; d < ND; ++d){
    s[d] = S[((size_t)o * ND + d) * NB + b];
    s2 = fmaf(s[d], s[d], s2);
  }
  float sc = (s2 / (1.f + s2)) / (sqrtf(s2) + 1e-8f);
  #pragma unroll
  for (int d = 0; d < ND; ++d) out[((size_t)b * NO + o) * ND + d] = s[d] * sc;
}

extern "C" void kernel_launch(void* const* d_in, const int* in_sizes, int n_in,
                              void* d_out, int out_size, void* d_ws, size_t ws_size,
                              hipStream_t stream){
  const float* x = (const float*)d_in[0];
  // d_in[1] (y) unused by the reference computation.
  const float* W = (const float*)d_in[2];
  float* out = (float*)d_out;
  char* ws = (char*)d_ws;

  const size_t xT_b  = (size_t)NI * NK * NB * sizeof(float);            // 9.4 MB
  const size_t usq_b = (size_t)NO * NI * NB * sizeof(float);            // 11.8 MB
  const size_t L_b   = usq_b;
  const size_t C_b   = usq_b;
  const size_t P_b   = (size_t)NCHUNK * NO * ND * NB * sizeof(float);   // 11.8 MB
  const size_t S_b   = (size_t)NO * ND * NB * sizeof(float);            // 160 KB

  size_t off = 0;
  float* xT  = (float*)(ws + off); off += xT_b;
  float* usq = (float*)(ws + off); off += usq_b;
  float* L   = (float*)(ws + off); off += L_b;
  float* C   = (float*)(ws + off); off += C_b;
  float* P   = (float*)(ws + off); off += P_b;
  float* S   = (float*)(ws + off); off += S_b;
  (void)ws_size; (void)in_sizes; (void)n_in; (void)out_size;

  k_transpose<<<dim3((NI * NK) / 32, NB / 32), dim3(32, 8), 0, stream>>>(x, xT);

  // iteration 0: uniform c = 0.1  ->  S, usq
  k_pass0<<<dim3(NCHUNK, NO), 256, 0, stream>>>(xT, W, usq, P);
  k_red<<<dim3(ND, NO), 256, 0, stream>>>(P, S);
  k_dot<true, true><<<dim3(NI), 256, 0, stream>>>(xT, W, usq, S, L, C);

  // iteration 1
  k_acc<<<dim3(NCHUNK, NO), 256, 0, stream>>>(xT, W, C, P);
  k_red<<<dim3(ND, NO), 256, 0, stream>>>(P, S);
  k_dot<false, false><<<dim3(NI), 256, 0, stream>>>(xT, W, usq, S, L, C);

  // iteration 2 (final accumulation) + squash
  k_acc<<<dim3(NCHUNK, NO), 256, 0, stream>>>(xT, W, C, P);
  k_red<<<dim3(ND, NO), 256, 0, stream>>>(P, S);
  k_final<<<dim3(NO), 256, 0, stream>>>(S, out);
}